// Round 1
// baseline (1923.261 us; speedup 1.0000x reference)
//
#include <hip/hip_runtime.h>
#include <hip/hip_bf16.h>
#include <math.h>

// ArcFace loss, fp32 reference-faithful implementation.
// B=2048, D=512, C=50000. Output: scalar mean NLL (f32).
//
// Pipeline:
//   k_norm_emb : emb_n[b][d] = emb / max(||emb_b||, eps)          (ws)
//   k_winv     : winv[c] = 1 / max(||w_c||, eps)                  (ws)
//   k_gemm     : per (64-row x 512-class) block: fp32 tiled GEMM,
//                online (max, sumexp) partial per row per 512-class chunk
//   k_finalize : per row: label logit recomputed exactly, margin swap,
//                logsumexp merge of 98 partials -> nll[b]
//   k_reduce   : mean(nll) -> d_out[0]

#define B_ROWS   2048
#define D_DIM    512
#define C_CLASSES 50000
#define ARC_MARGIN 0.3f
#define ARC_SCALE  30.0f
#define ARC_EPS    1e-12f

#define BM 64
#define BN 64
#define BK 32
#define NGROUP 8                    // classes per block = BN*NGROUP = 512
#define CHUNK  (BN * NGROUP)        // 512
#define NCHUNK 98                   // ceil(50000 / 512)

// workspace layout (bytes)
#define OFF_EMBN 0u                         // 2048*512*4   = 4,194,304
#define OFF_WINV 4194304u                   // 50000*4      =   200,000
#define OFF_PART 4394304u                   // 2048*98*2*4  = 1,605,632
#define OFF_NLL  5999936u                   // 2048*4       =     8,192
// total ~6.0 MB

__global__ __launch_bounds__(256) void k_norm_emb(const float* __restrict__ emb,
                                                  float* __restrict__ emb_n) {
    int w    = (blockIdx.x * blockDim.x + threadIdx.x) >> 6;   // one wave per row
    int lane = threadIdx.x & 63;
    const float4* src = (const float4*)(emb + (size_t)w * D_DIM);
    float4* dst       = (float4*)(emb_n + (size_t)w * D_DIM);
    float4 v0 = src[lane];
    float4 v1 = src[lane + 64];
    float s = v0.x*v0.x + v0.y*v0.y + v0.z*v0.z + v0.w*v0.w
            + v1.x*v1.x + v1.y*v1.y + v1.z*v1.z + v1.w*v1.w;
    #pragma unroll
    for (int off = 32; off; off >>= 1) s += __shfl_xor(s, off);
    float r = 1.0f / fmaxf(sqrtf(s), ARC_EPS);
    v0.x *= r; v0.y *= r; v0.z *= r; v0.w *= r;
    v1.x *= r; v1.y *= r; v1.z *= r; v1.w *= r;
    dst[lane]      = v0;
    dst[lane + 64] = v1;
}

__global__ __launch_bounds__(256) void k_winv(const float* __restrict__ weight,
                                              float* __restrict__ winv) {
    int w    = (blockIdx.x * blockDim.x + threadIdx.x) >> 6;   // one wave per class
    int lane = threadIdx.x & 63;
    if (w >= C_CLASSES) return;
    const float4* src = (const float4*)(weight + (size_t)w * D_DIM);
    float4 v0 = src[lane];
    float4 v1 = src[lane + 64];
    float s = v0.x*v0.x + v0.y*v0.y + v0.z*v0.z + v0.w*v0.w
            + v1.x*v1.x + v1.y*v1.y + v1.z*v1.z + v1.w*v1.w;
    #pragma unroll
    for (int off = 32; off; off >>= 1) s += __shfl_xor(s, off);
    if (lane == 0) winv[w] = 1.0f / fmaxf(sqrtf(s), ARC_EPS);
}

__global__ __launch_bounds__(256) void k_gemm(const float* __restrict__ embn,
                                              const float* __restrict__ weight,
                                              const float* __restrict__ winv,
                                              float2* __restrict__ partials) {
    // LDS padded to stride 68 so ds_read_b128 stays 16B-aligned.
    __shared__ float As[BK][BM + 4];
    __shared__ float Bs[BK][BN + 4];

    int tid = threadIdx.x;
    int tx  = tid & 15;            // 0..15 -> 4 cols each
    int ty  = tid >> 4;            // 0..15 -> 4 rows each
    int b0  = blockIdx.y * BM;
    int chunk  = blockIdx.x;
    int c_base = chunk * CHUNK;

    float row_m[4], row_s[4];
    #pragma unroll
    for (int i = 0; i < 4; ++i) { row_m[i] = -INFINITY; row_s[i] = 0.0f; }

    for (int g = 0; g < NGROUP; ++g) {
        int c0 = c_base + g * BN;
        float acc[4][4] = {};

        for (int kk = 0; kk < D_DIM; kk += BK) {
            // stage A tile (64 rows x 32 k), transposed into As[k][row]
            #pragma unroll
            for (int l = 0; l < 2; ++l) {
                int f   = tid + l * 256;
                int row = f >> 3;          // 8 float4 per row
                int kq  = f & 7;
                float4 v = *(const float4*)(embn + (size_t)(b0 + row) * D_DIM + kk + kq * 4);
                As[kq*4+0][row] = v.x; As[kq*4+1][row] = v.y;
                As[kq*4+2][row] = v.z; As[kq*4+3][row] = v.w;
            }
            // stage B tile (64 classes x 32 k), transposed into Bs[k][col]
            #pragma unroll
            for (int l = 0; l < 2; ++l) {
                int f   = tid + l * 256;
                int col = f >> 3;
                int kq  = f & 7;
                int c   = c0 + col;
                float4 v = make_float4(0.f, 0.f, 0.f, 0.f);
                if (c < C_CLASSES)
                    v = *(const float4*)(weight + (size_t)c * D_DIM + kk + kq * 4);
                Bs[kq*4+0][col] = v.x; Bs[kq*4+1][col] = v.y;
                Bs[kq*4+2][col] = v.z; Bs[kq*4+3][col] = v.w;
            }
            __syncthreads();
            #pragma unroll
            for (int k = 0; k < BK; ++k) {
                float a[4], bb[4];
                #pragma unroll
                for (int i = 0; i < 4; ++i) a[i]  = As[k][ty*4 + i];
                #pragma unroll
                for (int j = 0; j < 4; ++j) bb[j] = Bs[k][tx*4 + j];
                #pragma unroll
                for (int i = 0; i < 4; ++i)
                    #pragma unroll
                    for (int j = 0; j < 4; ++j)
                        acc[i][j] += a[i] * bb[j];
            }
            __syncthreads();
        }

        // epilogue for this 64-class group: per-row online (max, sumexp)
        #pragma unroll
        for (int i = 0; i < 4; ++i) {
            float lm = -INFINITY, ls = 0.0f;
            #pragma unroll
            for (int j = 0; j < 4; ++j) {
                int c = c0 + tx * 4 + j;
                if (c < C_CLASSES) {
                    float l = ARC_SCALE * (acc[i][j] * winv[c]);
                    if (l > lm) { ls = ls * expf(lm - l) + 1.0f; lm = l; }
                    else        { ls += expf(l - lm); }
                }
            }
            // butterfly merge across the 16 lanes sharing this row
            #pragma unroll
            for (int off = 1; off < 16; off <<= 1) {
                float om = __shfl_xor(lm, off);
                float os = __shfl_xor(ls, off);
                float m  = fmaxf(lm, om);
                float s  = (m == -INFINITY) ? 0.0f
                          : ls * expf(lm - m) + os * expf(om - m);
                lm = m; ls = s;
            }
            // fold into running per-row accumulator
            float m = fmaxf(row_m[i], lm);
            if (m != -INFINITY) {
                row_s[i] = row_s[i] * expf(row_m[i] - m) + ls * expf(lm - m);
                row_m[i] = m;
            }
        }
    }

    if (tx == 0) {
        #pragma unroll
        for (int i = 0; i < 4; ++i) {
            int b = b0 + ty * 4 + i;
            partials[(size_t)b * NCHUNK + chunk] = make_float2(row_m[i], row_s[i]);
        }
    }
}

__global__ __launch_bounds__(256) void k_finalize(const float* __restrict__ embn,
                                                  const float* __restrict__ weight,
                                                  const float* __restrict__ winv,
                                                  const int* __restrict__ labels,
                                                  const float2* __restrict__ partials,
                                                  float* __restrict__ nll) {
    int b    = (blockIdx.x * blockDim.x + threadIdx.x) >> 6;   // one wave per row
    int lane = threadIdx.x & 63;
    int label = labels[b];

    // exact label logit: dot(emb_n[b], w[label]) * winv[label]
    const float4* e  = (const float4*)(embn + (size_t)b * D_DIM);
    const float4* wt = (const float4*)(weight + (size_t)label * D_DIM);
    float4 e0 = e[lane],  e1 = e[lane + 64];
    float4 w0 = wt[lane], w1 = wt[lane + 64];
    float dot = e0.x*w0.x + e0.y*w0.y + e0.z*w0.z + e0.w*w0.w
              + e1.x*w1.x + e1.y*w1.y + e1.z*w1.z + e1.w*w1.w;
    #pragma unroll
    for (int off = 32; off; off >>= 1) dot += __shfl_xor(dot, off);

    float cosv   = dot * winv[label];
    float l_orig = ARC_SCALE * cosv;
    float l_adj  = ARC_SCALE * (cosv - ARC_MARGIN);

    // merge the 98 chunk partials (logsumexp state)
    float lm = -INFINITY, ls = 0.0f;
    for (int idx = lane; idx < NCHUNK; idx += 64) {
        float2 p = partials[(size_t)b * NCHUNK + idx];
        float m = fmaxf(lm, p.x);
        if (m != -INFINITY) {
            ls = ls * expf(lm - m) + p.y * expf(p.x - m);
            lm = m;
        }
    }
    #pragma unroll
    for (int off = 1; off < 64; off <<= 1) {
        float om = __shfl_xor(lm, off);
        float os = __shfl_xor(ls, off);
        float m  = fmaxf(lm, om);
        float s  = (m == -INFINITY) ? 0.0f
                  : ls * expf(lm - m) + os * expf(om - m);
        lm = m; ls = s;
    }

    // swap unmargined label term for margin-adjusted one, then NLL
    float s_adj = ls - expf(l_orig - lm) + expf(l_adj - lm);
    float v = lm + logf(s_adj) - l_adj;
    if (lane == 0) nll[b] = v;
}

__global__ __launch_bounds__(256) void k_reduce(const float* __restrict__ nll,
                                                float* __restrict__ out) {
    __shared__ float sm[256];
    float s = 0.0f;
    for (int i = threadIdx.x; i < B_ROWS; i += 256) s += nll[i];
    sm[threadIdx.x] = s;
    __syncthreads();
    for (int o = 128; o; o >>= 1) {
        if (threadIdx.x < o) sm[threadIdx.x] += sm[threadIdx.x + o];
        __syncthreads();
    }
    if (threadIdx.x == 0) out[0] = sm[0] / (float)B_ROWS;
}

extern "C" void kernel_launch(void* const* d_in, const int* in_sizes, int n_in,
                              void* d_out, int out_size, void* d_ws, size_t ws_size,
                              hipStream_t stream) {
    const float* emb    = (const float*)d_in[0];   // (2048, 512) f32
    const int*   labels = (const int*)d_in[1];     // (2048,) int32
    const float* weight = (const float*)d_in[2];   // (50000, 512) f32
    float* out = (float*)d_out;

    char* ws = (char*)d_ws;
    float*  emb_n    = (float*)(ws + OFF_EMBN);
    float*  winv     = (float*)(ws + OFF_WINV);
    float2* partials = (float2*)(ws + OFF_PART);
    float*  nll      = (float*)(ws + OFF_NLL);

    // 1 wave per row
    k_norm_emb<<<B_ROWS / 4, 256, 0, stream>>>(emb, emb_n);
    k_winv<<<(C_CLASSES + 3) / 4, 256, 0, stream>>>(weight, winv);

    dim3 grid(NCHUNK, B_ROWS / BM);  // 98 x 32
    k_gemm<<<grid, 256, 0, stream>>>(emb_n, weight, winv, partials);

    k_finalize<<<B_ROWS / 4, 256, 0, stream>>>(emb_n, weight, winv, labels,
                                               partials, nll);
    k_reduce<<<1, 256, 0, stream>>>(nll, out);
}

// Round 2
// 343.766 us; speedup vs baseline: 5.5947x; 5.5947x over previous
//
#include <hip/hip_runtime.h>
#include <hip/hip_bf16.h>
#include <math.h>
#include <stdint.h>

// ArcFace loss, bf16-MFMA GEMM + fused online softmax.
// B=2048, D=512, C=50000. Output: scalar mean NLL (f32).
//
//   k_prep_emb : normalize emb rows, write bf16 emb_n + einv (fp32)
//   k_prep_w   : normalize weight rows, write bf16 wn (padded to 50048) + winv
//   k_gemm     : 128x128 tile MFMA GEMM (16x16x32 bf16), online (max,sumexp)
//                partial per row per 128-class chunk -> partials[b][chunk]
//   k_finalize : exact fp32 label logit, margin swap, merge 391 partials
//   k_reduce   : mean(nll) -> d_out[0]

#define B_ROWS    2048
#define D_DIM     512
#define C_CLASSES 50000
#define C_PAD     50048            // 391 * 128
#define NCHUNK    391
#define ARC_MARGIN 0.3f
#define ARC_SCALE  30.0f
#define ARC_EPS    1e-12f

// workspace layout (bytes)
#define OFF_WN    0u               // 50048*512*2 = 51,249,152
#define OFF_EMBN  51249152u        // 2048*512*2  =  2,097,152
#define OFF_WINV  53346304u        // 50000*4     =    200,000
#define OFF_EINV  53546496u        // 2048*4      =      8,192
#define OFF_PART  53554688u        // 2048*391*8  =  6,406,144
#define OFF_NLL   59960832u        // 2048*4
// total ~57.2 MB

typedef __attribute__((ext_vector_type(8))) short  bf16x8;
typedef __attribute__((ext_vector_type(4))) float  f32x4;

typedef __attribute__((address_space(1))) const unsigned int g_u32;
typedef __attribute__((address_space(3))) unsigned int       l_u32;

__device__ __forceinline__ void gload_lds16(const void* g, void* l) {
    // dest is wave-uniform LDS base; HW writes lane i at base + i*16
    g_u32* gp = (g_u32*)(uintptr_t)g;
    l_u32* lp = (l_u32*)(uintptr_t)l;
    __builtin_amdgcn_global_load_lds(gp, lp, 16, 0, 0);
}

__device__ __forceinline__ unsigned short f2bf(float f) {
    union { float f; unsigned u; } v; v.f = f;
    unsigned r = v.u + 0x7FFFu + ((v.u >> 16) & 1u);   // round-to-nearest-even
    return (unsigned short)(r >> 16);
}

// ---------------- prep: embeddings -> bf16 normalized ----------------
__global__ __launch_bounds__(256) void k_prep_emb(const float* __restrict__ emb,
                                                  unsigned short* __restrict__ embn,
                                                  float* __restrict__ einv) {
    int row  = (blockIdx.x * blockDim.x + threadIdx.x) >> 6;
    int lane = threadIdx.x & 63;
    const float4* r4 = (const float4*)(emb + (size_t)row * D_DIM);
    float4 v0 = r4[lane * 2];
    float4 v1 = r4[lane * 2 + 1];
    float s = v0.x*v0.x + v0.y*v0.y + v0.z*v0.z + v0.w*v0.w
            + v1.x*v1.x + v1.y*v1.y + v1.z*v1.z + v1.w*v1.w;
    #pragma unroll
    for (int off = 32; off; off >>= 1) s += __shfl_xor(s, off);
    float r = 1.0f / fmaxf(sqrtf(s), ARC_EPS);
    if (lane == 0) einv[row] = r;
    bf16x8 o;
    o[0] = (short)f2bf(v0.x * r); o[1] = (short)f2bf(v0.y * r);
    o[2] = (short)f2bf(v0.z * r); o[3] = (short)f2bf(v0.w * r);
    o[4] = (short)f2bf(v1.x * r); o[5] = (short)f2bf(v1.y * r);
    o[6] = (short)f2bf(v1.z * r); o[7] = (short)f2bf(v1.w * r);
    *(bf16x8*)(embn + (size_t)row * D_DIM + lane * 8) = o;
}

// ---------------- prep: weight -> bf16 normalized (padded) ----------------
__global__ __launch_bounds__(256) void k_prep_w(const float* __restrict__ weight,
                                                unsigned short* __restrict__ wn,
                                                float* __restrict__ winv) {
    int row  = (blockIdx.x * blockDim.x + threadIdx.x) >> 6;
    int lane = threadIdx.x & 63;
    if (row >= C_PAD) return;
    if (row >= C_CLASSES) {                 // zero-fill pad classes
        bf16x8 z = {0,0,0,0,0,0,0,0};
        *(bf16x8*)(wn + (size_t)row * D_DIM + lane * 8) = z;
        return;
    }
    const float4* r4 = (const float4*)(weight + (size_t)row * D_DIM);
    float4 v0 = r4[lane * 2];
    float4 v1 = r4[lane * 2 + 1];
    float s = v0.x*v0.x + v0.y*v0.y + v0.z*v0.z + v0.w*v0.w
            + v1.x*v1.x + v1.y*v1.y + v1.z*v1.z + v1.w*v1.w;
    #pragma unroll
    for (int off = 32; off; off >>= 1) s += __shfl_xor(s, off);
    float r = 1.0f / fmaxf(sqrtf(s), ARC_EPS);
    if (lane == 0) winv[row] = r;
    bf16x8 o;
    o[0] = (short)f2bf(v0.x * r); o[1] = (short)f2bf(v0.y * r);
    o[2] = (short)f2bf(v0.z * r); o[3] = (short)f2bf(v0.w * r);
    o[4] = (short)f2bf(v1.x * r); o[5] = (short)f2bf(v1.y * r);
    o[6] = (short)f2bf(v1.z * r); o[7] = (short)f2bf(v1.w * r);
    *(bf16x8*)(wn + (size_t)row * D_DIM + lane * 8) = o;
}

// ---------------- GEMM + fused online softmax partials ----------------
__global__ __launch_bounds__(256) void k_gemm(const unsigned short* __restrict__ embn,
                                              const unsigned short* __restrict__ wn,
                                              float2* __restrict__ partials) {
    __shared__ unsigned short A_s[128 * 32];   // [row][k] 64 B/row
    __shared__ unsigned short B_s[128 * 32];   // [col][k]
    __shared__ float2 Red[128][2];

    const int tid    = threadIdx.x;
    const int w      = tid >> 6;        // wave 0..3
    const int lane   = tid & 63;
    const int lanelo = lane & 15;
    const int quad   = lane >> 4;
    const int wrow0  = (w >> 1) * 64;   // wave's row base in tile
    const int wcol0  = (w & 1) * 64;    // wave's col base in tile
    const int b0     = blockIdx.y * 128;
    const int n0     = blockIdx.x * 128;

    const unsigned short* Abase = embn + (size_t)b0 * D_DIM;
    const unsigned short* Bbase = wn   + (size_t)n0 * D_DIM;

    f32x4 acc[4][4];
    #pragma unroll
    for (int i = 0; i < 4; ++i)
        #pragma unroll
        for (int j = 0; j < 4; ++j)
            acc[i][j] = (f32x4){0.f, 0.f, 0.f, 0.f};

    // staging: per wave-instr, 16 rows x 32k (1024 B); lane l -> row l>>2, kq l&3
    const int srow = lane >> 2;
    const int skq  = (lane & 3) * 8;

    for (int kt = 0; kt < D_DIM / 32; ++kt) {
        const int kk = kt * 32;
        #pragma unroll
        for (int t = 0; t < 2; ++t) {
            const int r0 = w * 32 + t * 16;
            gload_lds16(Abase + (size_t)(r0 + srow) * D_DIM + kk + skq, &A_s[r0 * 32]);
            gload_lds16(Bbase + (size_t)(r0 + srow) * D_DIM + kk + skq, &B_s[r0 * 32]);
        }
        __syncthreads();

        bf16x8 af[4], bfr[4];
        #pragma unroll
        for (int i = 0; i < 4; ++i)
            af[i] = *(const bf16x8*)&A_s[(wrow0 + i * 16 + lanelo) * 32 + quad * 8];
        #pragma unroll
        for (int j = 0; j < 4; ++j)
            bfr[j] = *(const bf16x8*)&B_s[(wcol0 + j * 16 + lanelo) * 32 + quad * 8];

        #pragma unroll
        for (int i = 0; i < 4; ++i)
            #pragma unroll
            for (int j = 0; j < 4; ++j)
                acc[i][j] = __builtin_amdgcn_mfma_f32_16x16x32_bf16(af[i], bfr[j], acc[i][j], 0, 0, 0);
        __syncthreads();
    }

    // epilogue: C/D layout col=lane&15, row=quad*4+reg
    #pragma unroll
    for (int i = 0; i < 4; ++i) {
        #pragma unroll
        for (int reg = 0; reg < 4; ++reg) {
            float lg[4];
            float m4 = -INFINITY;
            #pragma unroll
            for (int j = 0; j < 4; ++j) {
                int c = n0 + wcol0 + j * 16 + lanelo;
                lg[j] = (c < C_CLASSES) ? ARC_SCALE * acc[i][j][reg] : -INFINITY;
                m4 = fmaxf(m4, lg[j]);
            }
            float s4 = 0.f;
            #pragma unroll
            for (int j = 0; j < 4; ++j)
                s4 += __expf(lg[j] - m4);        // -inf -> 0 (m4 always finite)
            #pragma unroll
            for (int off = 1; off < 16; off <<= 1) {
                float om = __shfl_xor(m4, off);
                float os = __shfl_xor(s4, off);
                float nm = fmaxf(m4, om);
                s4 = s4 * __expf(m4 - nm) + os * __expf(om - nm);
                m4 = nm;
            }
            if (lanelo == 0)
                Red[wrow0 + i * 16 + quad * 4 + reg][w & 1] = make_float2(m4, s4);
        }
    }
    __syncthreads();

    if (tid < 128) {
        float2 p0 = Red[tid][0], p1 = Red[tid][1];
        float m = fmaxf(p0.x, p1.x);
        float s = p0.y * __expf(p0.x - m) + p1.y * __expf(p1.x - m);
        partials[(size_t)(b0 + tid) * NCHUNK + blockIdx.x] = make_float2(m, s);
    }
}

// ---------------- finalize: label logit + LSE merge -> nll ----------------
__global__ __launch_bounds__(256) void k_finalize(const float* __restrict__ emb,
                                                  const float* __restrict__ weight,
                                                  const float* __restrict__ einv,
                                                  const float* __restrict__ winv,
                                                  const int* __restrict__ labels,
                                                  const float2* __restrict__ partials,
                                                  float* __restrict__ nll) {
    int b    = (blockIdx.x * blockDim.x + threadIdx.x) >> 6;
    int lane = threadIdx.x & 63;
    int label = labels[b];

    const float4* e  = (const float4*)(emb + (size_t)b * D_DIM);
    const float4* wt = (const float4*)(weight + (size_t)label * D_DIM);
    float4 e0 = e[lane],  e1 = e[lane + 64];
    float4 w0 = wt[lane], w1 = wt[lane + 64];
    float dot = e0.x*w0.x + e0.y*w0.y + e0.z*w0.z + e0.w*w0.w
              + e1.x*w1.x + e1.y*w1.y + e1.z*w1.z + e1.w*w1.w;
    #pragma unroll
    for (int off = 32; off; off >>= 1) dot += __shfl_xor(dot, off);

    float cosv   = dot * einv[b] * winv[label];
    float l_orig = ARC_SCALE * cosv;
    float l_adj  = ARC_SCALE * (cosv - ARC_MARGIN);

    float lm = -INFINITY, ls = 0.0f;
    for (int idx = lane; idx < NCHUNK; idx += 64) {
        float2 p = partials[(size_t)b * NCHUNK + idx];
        float m = fmaxf(lm, p.x);
        ls = ls * __expf(lm - m) + p.y * __expf(p.x - m);
        lm = m;
    }
    #pragma unroll
    for (int off = 1; off < 64; off <<= 1) {
        float om = __shfl_xor(lm, off);
        float os = __shfl_xor(ls, off);
        float m  = fmaxf(lm, om);
        float s  = (m == -INFINITY) ? 0.0f
                  : ls * __expf(lm - m) + os * __expf(om - m);
        lm = m; ls = s;
    }

    float s_adj = ls - __expf(l_orig - lm) + __expf(l_adj - lm);
    float v = lm + logf(s_adj) - l_adj;
    if (lane == 0) nll[b] = v;
}

__global__ __launch_bounds__(256) void k_reduce(const float* __restrict__ nll,
                                                float* __restrict__ out) {
    __shared__ float sm[256];
    float s = 0.0f;
    for (int i = threadIdx.x; i < B_ROWS; i += 256) s += nll[i];
    sm[threadIdx.x] = s;
    __syncthreads();
    for (int o = 128; o; o >>= 1) {
        if (threadIdx.x < o) sm[threadIdx.x] += sm[threadIdx.x + o];
        __syncthreads();
    }
    if (threadIdx.x == 0) out[0] = sm[0] / (float)B_ROWS;
}

extern "C" void kernel_launch(void* const* d_in, const int* in_sizes, int n_in,
                              void* d_out, int out_size, void* d_ws, size_t ws_size,
                              hipStream_t stream) {
    const float* emb    = (const float*)d_in[0];   // (2048, 512) f32
    const int*   labels = (const int*)d_in[1];     // (2048,)
    const float* weight = (const float*)d_in[2];   // (50000, 512) f32
    float* out = (float*)d_out;

    char* ws = (char*)d_ws;
    unsigned short* wn    = (unsigned short*)(ws + OFF_WN);
    unsigned short* embn  = (unsigned short*)(ws + OFF_EMBN);
    float*  winv     = (float*)(ws + OFF_WINV);
    float*  einv     = (float*)(ws + OFF_EINV);
    float2* partials = (float2*)(ws + OFF_PART);
    float*  nll      = (float*)(ws + OFF_NLL);

    k_prep_emb<<<B_ROWS / 4, 256, 0, stream>>>(emb, embn, einv);
    k_prep_w<<<C_PAD / 4, 256, 0, stream>>>(weight, wn, winv);

    dim3 grid(NCHUNK, B_ROWS / 128);   // 391 x 16
    k_gemm<<<grid, 256, 0, stream>>>(embn, wn, partials);

    k_finalize<<<B_ROWS / 4, 256, 0, stream>>>(emb, weight, einv, winv, labels,
                                               partials, nll);
    k_reduce<<<1, 256, 0, stream>>>(nll, out);
}

// Round 3
// 310.843 us; speedup vs baseline: 6.1872x; 1.1059x over previous
//
#include <hip/hip_runtime.h>
#include <hip/hip_bf16.h>
#include <math.h>
#include <stdint.h>

// ArcFace loss, bf16-MFMA GEMM + fused fixed-max softmax partials.
// B=2048, D=512, C=50000. Output: scalar mean NLL (f32).
//
// Key numerics: logits = 30*cos in [-30,30], so exp(l - 30) is always in
// [e^-60, 1] — no overflow, no underflow-to-zero of the total. We therefore
// use a FIXED max of 30 and accumulate plain sums (no online max tracking):
//   lse = 30 + log(sum_c exp(l_c - 30))
// This removes all exp-rescaling from the reduction tree.
//
//   k_prep_emb : normalize emb rows -> bf16 emb_n + einv (fp32)
//   k_prep_w   : normalize weight rows -> bf16 wn (padded to 50048) + winv
//   k_gemm     : 128x128 tile MFMA GEMM (16x16x32 bf16), per-row partial
//                sum exp(l-30) per 128-class chunk -> partials[b][chunk]
//   k_finalize : exact fp32 label logit, margin swap, sum 391 partials
//   k_reduce   : mean(nll) -> d_out[0]

#define B_ROWS    2048
#define D_DIM     512
#define C_CLASSES 50000
#define C_PAD     50048            // 391 * 128
#define NCHUNK    391
#define ARC_MARGIN 0.3f
#define ARC_SCALE  30.0f
#define ARC_EPS    1e-12f
// exp(l - 30) = exp2(cos*30*log2e - 30*log2e)
#define K_LOG2E_S  43.2808512f     // 30 * log2(e)

// workspace layout (bytes)
#define OFF_WN    0u               // 50048*512*2 = 51,249,152
#define OFF_EMBN  51249152u        // 2048*512*2  =  2,097,152
#define OFF_WINV  53346304u        // 50000*4     =    200,000
#define OFF_EINV  53546496u        // 2048*4      =      8,192
#define OFF_PART  53554688u        // 2048*391*4  =  3,203,072
#define OFF_NLL   56757760u        // 2048*4
// total ~54 MB

typedef __attribute__((ext_vector_type(8))) short  bf16x8;
typedef __attribute__((ext_vector_type(4))) float  f32x4;

typedef __attribute__((address_space(1))) const unsigned int g_u32;
typedef __attribute__((address_space(3))) unsigned int       l_u32;

__device__ __forceinline__ void gload_lds16(const void* g, void* l) {
    // dest is wave-uniform LDS base; HW writes lane i at base + i*16
    g_u32* gp = (g_u32*)(uintptr_t)g;
    l_u32* lp = (l_u32*)(uintptr_t)l;
    __builtin_amdgcn_global_load_lds(gp, lp, 16, 0, 0);
}

__device__ __forceinline__ unsigned short f2bf(float f) {
    union { float f; unsigned u; } v; v.f = f;
    unsigned r = v.u + 0x7FFFu + ((v.u >> 16) & 1u);   // round-to-nearest-even
    return (unsigned short)(r >> 16);
}

// ---------------- prep: embeddings -> bf16 normalized ----------------
__global__ __launch_bounds__(256) void k_prep_emb(const float* __restrict__ emb,
                                                  unsigned short* __restrict__ embn,
                                                  float* __restrict__ einv) {
    int row  = (blockIdx.x * blockDim.x + threadIdx.x) >> 6;
    int lane = threadIdx.x & 63;
    const float4* r4 = (const float4*)(emb + (size_t)row * D_DIM);
    float4 v0 = r4[lane * 2];
    float4 v1 = r4[lane * 2 + 1];
    float s = v0.x*v0.x + v0.y*v0.y + v0.z*v0.z + v0.w*v0.w
            + v1.x*v1.x + v1.y*v1.y + v1.z*v1.z + v1.w*v1.w;
    #pragma unroll
    for (int off = 32; off; off >>= 1) s += __shfl_xor(s, off);
    float r = 1.0f / fmaxf(sqrtf(s), ARC_EPS);
    if (lane == 0) einv[row] = r;
    bf16x8 o;
    o[0] = (short)f2bf(v0.x * r); o[1] = (short)f2bf(v0.y * r);
    o[2] = (short)f2bf(v0.z * r); o[3] = (short)f2bf(v0.w * r);
    o[4] = (short)f2bf(v1.x * r); o[5] = (short)f2bf(v1.y * r);
    o[6] = (short)f2bf(v1.z * r); o[7] = (short)f2bf(v1.w * r);
    *(bf16x8*)(embn + (size_t)row * D_DIM + lane * 8) = o;
}

// ---------------- prep: weight -> bf16 normalized (padded) ----------------
__global__ __launch_bounds__(256) void k_prep_w(const float* __restrict__ weight,
                                                unsigned short* __restrict__ wn,
                                                float* __restrict__ winv) {
    int row  = (blockIdx.x * blockDim.x + threadIdx.x) >> 6;
    int lane = threadIdx.x & 63;
    if (row >= C_PAD) return;
    if (row >= C_CLASSES) {                 // zero-fill pad classes
        bf16x8 z = {0,0,0,0,0,0,0,0};
        *(bf16x8*)(wn + (size_t)row * D_DIM + lane * 8) = z;
        return;
    }
    const float4* r4 = (const float4*)(weight + (size_t)row * D_DIM);
    float4 v0 = r4[lane * 2];
    float4 v1 = r4[lane * 2 + 1];
    float s = v0.x*v0.x + v0.y*v0.y + v0.z*v0.z + v0.w*v0.w
            + v1.x*v1.x + v1.y*v1.y + v1.z*v1.z + v1.w*v1.w;
    #pragma unroll
    for (int off = 32; off; off >>= 1) s += __shfl_xor(s, off);
    float r = 1.0f / fmaxf(sqrtf(s), ARC_EPS);
    if (lane == 0) winv[row] = r;
    bf16x8 o;
    o[0] = (short)f2bf(v0.x * r); o[1] = (short)f2bf(v0.y * r);
    o[2] = (short)f2bf(v0.z * r); o[3] = (short)f2bf(v0.w * r);
    o[4] = (short)f2bf(v1.x * r); o[5] = (short)f2bf(v1.y * r);
    o[6] = (short)f2bf(v1.z * r); o[7] = (short)f2bf(v1.w * r);
    *(bf16x8*)(wn + (size_t)row * D_DIM + lane * 8) = o;
}

struct TrueT  { static constexpr bool value = true;  };
struct FalseT { static constexpr bool value = false; };

// ---------------- GEMM + fused fixed-max softmax partials ----------------
__global__ __launch_bounds__(256) void k_gemm(const unsigned short* __restrict__ embn,
                                              const unsigned short* __restrict__ wn,
                                              float* __restrict__ partials) {
    __shared__ unsigned short A_s[128 * 32];   // [row][k] 64 B/row
    __shared__ unsigned short B_s[128 * 32];   // [col][k]
    __shared__ float Red[128][2];

    const int tid    = threadIdx.x;
    const int w      = tid >> 6;        // wave 0..3
    const int lane   = tid & 63;
    const int lanelo = lane & 15;
    const int quad   = lane >> 4;
    const int wrow0  = (w >> 1) * 64;   // wave's row base in tile
    const int wcol0  = (w & 1) * 64;    // wave's col base in tile
    // grid: x = row-block (fast) -> concurrent blocks share B chunks (L2)
    const int b0     = blockIdx.x * 128;
    const int chunk  = blockIdx.y;
    const int n0     = chunk * 128;

    const unsigned short* Abase = embn + (size_t)b0 * D_DIM;
    const unsigned short* Bbase = wn   + (size_t)n0 * D_DIM;

    f32x4 acc[4][4];
    #pragma unroll
    for (int i = 0; i < 4; ++i)
        #pragma unroll
        for (int j = 0; j < 4; ++j)
            acc[i][j] = (f32x4){0.f, 0.f, 0.f, 0.f};

    // staging: per wave-instr, 16 rows x 32k (1024 B); lane l -> row l>>2, kq l&3
    const int srow = lane >> 2;
    const int skq  = (lane & 3) * 8;

    for (int kt = 0; kt < D_DIM / 32; ++kt) {
        const int kk = kt * 32;
        #pragma unroll
        for (int t = 0; t < 2; ++t) {
            const int r0 = w * 32 + t * 16;
            gload_lds16(Abase + (size_t)(r0 + srow) * D_DIM + kk + skq, &A_s[r0 * 32]);
            gload_lds16(Bbase + (size_t)(r0 + srow) * D_DIM + kk + skq, &B_s[r0 * 32]);
        }
        __syncthreads();

        bf16x8 af[4], bfr[4];
        #pragma unroll
        for (int i = 0; i < 4; ++i)
            af[i] = *(const bf16x8*)&A_s[(wrow0 + i * 16 + lanelo) * 32 + quad * 8];
        #pragma unroll
        for (int j = 0; j < 4; ++j)
            bfr[j] = *(const bf16x8*)&B_s[(wcol0 + j * 16 + lanelo) * 32 + quad * 8];

        #pragma unroll
        for (int i = 0; i < 4; ++i)
            #pragma unroll
            for (int j = 0; j < 4; ++j)
                acc[i][j] = __builtin_amdgcn_mfma_f32_16x16x32_bf16(af[i], bfr[j], acc[i][j], 0, 0, 0);
        __syncthreads();
    }

    // epilogue: C/D layout col=lane&15, row=quad*4+reg. Fixed max = 30:
    // term = exp2(acc*30*log2e - 30*log2e); plain-add reduction tree.
    auto epi = [&](auto maskTag) {
        constexpr bool MASK = decltype(maskTag)::value;
        #pragma unroll
        for (int i = 0; i < 4; ++i) {
            #pragma unroll
            for (int reg = 0; reg < 4; ++reg) {
                float s4 = 0.f;
                #pragma unroll
                for (int j = 0; j < 4; ++j) {
                    float t = __builtin_amdgcn_exp2f(
                        fmaf(acc[i][j][reg], K_LOG2E_S, -K_LOG2E_S));
                    if (MASK) {
                        int c = n0 + wcol0 + j * 16 + lanelo;
                        if (c >= C_CLASSES) t = 0.f;
                    }
                    s4 += t;
                }
                #pragma unroll
                for (int off = 1; off < 16; off <<= 1)
                    s4 += __shfl_xor(s4, off);
                if (lanelo == 0)
                    Red[wrow0 + i * 16 + quad * 4 + reg][w & 1] = s4;
            }
        }
    };
    if (chunk == NCHUNK - 1) epi(TrueT{}); else epi(FalseT{});
    __syncthreads();

    if (tid < 128)
        partials[(size_t)(b0 + tid) * NCHUNK + chunk] = Red[tid][0] + Red[tid][1];
}

// ---------------- finalize: label logit + partial sum -> nll ----------------
__global__ __launch_bounds__(256) void k_finalize(const float* __restrict__ emb,
                                                  const float* __restrict__ weight,
                                                  const float* __restrict__ einv,
                                                  const float* __restrict__ winv,
                                                  const int* __restrict__ labels,
                                                  const float* __restrict__ partials,
                                                  float* __restrict__ nll) {
    int b    = (blockIdx.x * blockDim.x + threadIdx.x) >> 6;
    int lane = threadIdx.x & 63;
    int label = labels[b];

    const float4* e  = (const float4*)(emb + (size_t)b * D_DIM);
    const float4* wt = (const float4*)(weight + (size_t)label * D_DIM);
    float4 e0 = e[lane],  e1 = e[lane + 64];
    float4 w0 = wt[lane], w1 = wt[lane + 64];
    float dot = e0.x*w0.x + e0.y*w0.y + e0.z*w0.z + e0.w*w0.w
              + e1.x*w1.x + e1.y*w1.y + e1.z*w1.z + e1.w*w1.w;
    float ls = 0.f;
    for (int idx = lane; idx < NCHUNK; idx += 64)
        ls += partials[(size_t)b * NCHUNK + idx];
    #pragma unroll
    for (int off = 32; off; off >>= 1) {
        dot += __shfl_xor(dot, off);
        ls  += __shfl_xor(ls, off);
    }

    float cosv   = dot * einv[b] * winv[label];
    float l_orig = ARC_SCALE * cosv;
    float l_adj  = ARC_SCALE * (cosv - ARC_MARGIN);

    // swap unmargined label term (as accumulated) for margin-adjusted one
    float s_adj = ls - __expf(l_orig - ARC_SCALE) + __expf(l_adj - ARC_SCALE);
    float v = ARC_SCALE + logf(s_adj) - l_adj;
    if (lane == 0) nll[b] = v;
}

__global__ __launch_bounds__(256) void k_reduce(const float* __restrict__ nll,
                                                float* __restrict__ out) {
    __shared__ float sm[256];
    float s = 0.0f;
    for (int i = threadIdx.x; i < B_ROWS; i += 256) s += nll[i];
    sm[threadIdx.x] = s;
    __syncthreads();
    for (int o = 128; o; o >>= 1) {
        if (threadIdx.x < o) sm[threadIdx.x] += sm[threadIdx.x + o];
        __syncthreads();
    }
    if (threadIdx.x == 0) out[0] = sm[0] / (float)B_ROWS;
}

extern "C" void kernel_launch(void* const* d_in, const int* in_sizes, int n_in,
                              void* d_out, int out_size, void* d_ws, size_t ws_size,
                              hipStream_t stream) {
    const float* emb    = (const float*)d_in[0];   // (2048, 512) f32
    const int*   labels = (const int*)d_in[1];     // (2048,)
    const float* weight = (const float*)d_in[2];   // (50000, 512) f32
    float* out = (float*)d_out;

    char* ws = (char*)d_ws;
    unsigned short* wn    = (unsigned short*)(ws + OFF_WN);
    unsigned short* embn  = (unsigned short*)(ws + OFF_EMBN);
    float* winv     = (float*)(ws + OFF_WINV);
    float* einv     = (float*)(ws + OFF_EINV);
    float* partials = (float*)(ws + OFF_PART);
    float* nll      = (float*)(ws + OFF_NLL);

    k_prep_emb<<<B_ROWS / 4, 256, 0, stream>>>(emb, embn, einv);
    k_prep_w<<<C_PAD / 4, 256, 0, stream>>>(weight, wn, winv);

    dim3 grid(B_ROWS / 128, NCHUNK);   // 16 x 391, row-block fast
    k_gemm<<<grid, 256, 0, stream>>>(embn, wn, partials);

    k_finalize<<<B_ROWS / 4, 256, 0, stream>>>(emb, weight, einv, winv, labels,
                                               partials, nll);
    k_reduce<<<1, 256, 0, stream>>>(nll, out);
}

// Round 4
// 271.966 us; speedup vs baseline: 7.0717x; 1.1429x over previous
//
#include <hip/hip_runtime.h>
#include <hip/hip_bf16.h>
#include <math.h>
#include <stdint.h>

// ArcFace loss via MX-fp8 (e4m3, identity scales) MFMA GEMM + fused
// fixed-max softmax. B=2048, D=512, C=50000. Output: scalar mean NLL (f32).
//
// Numerics: logits = 30*cos in [-30,30] -> fixed max 30, plain sums:
//   lse = 30 + log(sum_c exp(l_c - 30)); label logit recomputed exactly in
//   fp32 at finalize, so fp8 error only perturbs the softmax denominator.
//
//   k_prep : normalize emb+weight rows -> e4m3 (wq padded to 50048) + inv norms
//   k_gemm : 128x128 tile, mfma_scale_f32_16x16x128_f8f6f4 (scales = 1.0),
//            K-loop = 4 iters of BK=128, conflict-free [kc][row] LDS layout,
//            per-row sum exp(l-30) per 128-class chunk -> partials[b][chunk]
//   k_fin  : exact fp32 label logit, margin swap, sum 391 partials,
//            block-level atomicAdd of mean -> d_out[0] (memset to 0 first)

#define B_ROWS    2048
#define D_DIM     512
#define C_CLASSES 50000
#define C_PAD     50048            // 391 * 128
#define NCHUNK    391
#define ARC_MARGIN 0.3f
#define ARC_SCALE  30.0f
#define ARC_EPS    1e-12f
#define K_LOG2E_S  43.2808512f     // 30 * log2(e)

// workspace layout (bytes)
#define OFF_WQ    0u               // 50048*512 = 25,624,576
#define OFF_EMBQ  25624576u        // 2048*512  =  1,048,576
#define OFF_WINV  26673152u        // 50000*4   =    200,000
#define OFF_EINV  26873152u        // 2048*4    =      8,192
#define OFF_PART  26881344u        // 2048*391*4 = 3,203,072
// total ~30.1 MB

typedef __attribute__((ext_vector_type(8))) int   i32x8;
typedef __attribute__((ext_vector_type(4))) int   i32x4;
typedef __attribute__((ext_vector_type(4))) float f32x4;

typedef __attribute__((address_space(1))) const unsigned int g_u32;
typedef __attribute__((address_space(3))) unsigned int       l_u32;

__device__ __forceinline__ void gload_lds16(const void* g, void* l) {
    // dest is wave-uniform LDS base; HW writes lane i at base + i*16
    g_u32* gp = (g_u32*)(uintptr_t)g;
    l_u32* lp = (l_u32*)(uintptr_t)l;
    __builtin_amdgcn_global_load_lds(gp, lp, 16, 0, 0);
}

// ---------------- prep: rows -> normalized e4m3 + inverse norms ----------------
// gw < C_PAD: weight row (pad rows zero-filled); else: embedding row.
__global__ __launch_bounds__(256) void k_prep(const float* __restrict__ emb,
                                              const float* __restrict__ weight,
                                              uint8_t* __restrict__ embq,
                                              uint8_t* __restrict__ wq,
                                              float* __restrict__ einv,
                                              float* __restrict__ winv) {
    int gw   = (blockIdx.x * blockDim.x + threadIdx.x) >> 6;   // one wave per row
    int lane = threadIdx.x & 63;
    const float* src;
    uint8_t* dst;
    float* invout;
    if (gw < C_PAD) {
        if (gw >= C_CLASSES) {                // zero-fill pad classes
            *(int2*)(wq + (size_t)gw * D_DIM + lane * 8) = make_int2(0, 0);
            return;
        }
        src = weight + (size_t)gw * D_DIM;
        dst = wq + (size_t)gw * D_DIM;
        invout = winv + gw;
    } else {
        int row = gw - C_PAD;
        src = emb + (size_t)row * D_DIM;
        dst = embq + (size_t)row * D_DIM;
        invout = einv + row;
    }
    const float4* r4 = (const float4*)src;
    float4 v0 = r4[lane * 2];
    float4 v1 = r4[lane * 2 + 1];
    float s = v0.x*v0.x + v0.y*v0.y + v0.z*v0.z + v0.w*v0.w
            + v1.x*v1.x + v1.y*v1.y + v1.z*v1.z + v1.w*v1.w;
    #pragma unroll
    for (int off = 32; off; off >>= 1) s += __shfl_xor(s, off);
    float r = 1.0f / fmaxf(sqrtf(s), ARC_EPS);
    if (lane == 0) *invout = r;
    int p0 = __builtin_amdgcn_cvt_pk_fp8_f32(v0.x * r, v0.y * r, 0, false);
    p0     = __builtin_amdgcn_cvt_pk_fp8_f32(v0.z * r, v0.w * r, p0, true);
    int p1 = __builtin_amdgcn_cvt_pk_fp8_f32(v1.x * r, v1.y * r, 0, false);
    p1     = __builtin_amdgcn_cvt_pk_fp8_f32(v1.z * r, v1.w * r, p1, true);
    *(int2*)(dst + lane * 8) = make_int2(p0, p1);
}

struct TrueT  { static constexpr bool value = true;  };
struct FalseT { static constexpr bool value = false; };

// ---------------- GEMM (MX-fp8, identity scales) + softmax partials -----------
__global__ __launch_bounds__(256) void k_gemm(const uint8_t* __restrict__ embq,
                                              const uint8_t* __restrict__ wq,
                                              float* __restrict__ partials) {
    // layout: 8 row-blocks of 16 rows; within block: [kc 0..7][row 0..15] x 16B
    // stage lane l -> row l&15, kc (l>>4)+4h  => dst base + l*16 (contiguous)
    // frag read: 16 consecutive lanes read 256 contiguous B -> conflict-free
    __shared__ __align__(16) uint8_t A_s[128 * 128];
    __shared__ __align__(16) uint8_t B_s[128 * 128];
    __shared__ float Red[128][2];

    const int tid    = threadIdx.x;
    const int w      = tid >> 6;        // wave 0..3
    const int lane   = tid & 63;
    const int lanelo = lane & 15;
    const int quad   = lane >> 4;
    const int wrow0  = (w >> 1) * 64;   // wave's row base in tile
    const int wcol0  = (w & 1) * 64;    // wave's col base in tile
    const int b0     = blockIdx.x * 128;   // row-block fast -> share B in L2
    const int chunk  = blockIdx.y;
    const int n0     = chunk * 128;

    const uint8_t* Abase = embq + (size_t)b0 * D_DIM;
    const uint8_t* Bbase = wq   + (size_t)n0 * D_DIM;

    f32x4 acc[4][4];
    #pragma unroll
    for (int i = 0; i < 4; ++i)
        #pragma unroll
        for (int j = 0; j < 4; ++j)
            acc[i][j] = (f32x4){0.f, 0.f, 0.f, 0.f};

    const int srow = lane & 15;
    const int skc  = lane >> 4;

    for (int kt = 0; kt < 4; ++kt) {
        const int k0 = kt * 128;
        #pragma unroll
        for (int t = 0; t < 2; ++t) {
            const int rb = w * 2 + t;           // 0..7 across waves
            #pragma unroll
            for (int h = 0; h < 2; ++h) {
                const int kc = h * 4 + skc;     // 0..7
                gload_lds16(Abase + (size_t)(rb * 16 + srow) * D_DIM + k0 + kc * 16,
                            &A_s[rb * 2048 + h * 1024]);
                gload_lds16(Bbase + (size_t)(rb * 16 + srow) * D_DIM + k0 + kc * 16,
                            &B_s[rb * 2048 + h * 1024]);
            }
        }
        __syncthreads();

        i32x8 af[4], bfr[4];
        #pragma unroll
        for (int i = 0; i < 4; ++i) {
            const int rb = (w >> 1) * 4 + i;
            i32x4 lo = *(const i32x4*)&A_s[rb * 2048 + quad * 512 + lanelo * 16];
            i32x4 hi = *(const i32x4*)&A_s[rb * 2048 + quad * 512 + 256 + lanelo * 16];
            af[i] = (i32x8){lo[0], lo[1], lo[2], lo[3], hi[0], hi[1], hi[2], hi[3]};
        }
        #pragma unroll
        for (int j = 0; j < 4; ++j) {
            const int rb = (w & 1) * 4 + j;
            i32x4 lo = *(const i32x4*)&B_s[rb * 2048 + quad * 512 + lanelo * 16];
            i32x4 hi = *(const i32x4*)&B_s[rb * 2048 + quad * 512 + 256 + lanelo * 16];
            bfr[j] = (i32x8){lo[0], lo[1], lo[2], lo[3], hi[0], hi[1], hi[2], hi[3]};
        }

        #pragma unroll
        for (int i = 0; i < 4; ++i)
            #pragma unroll
            for (int j = 0; j < 4; ++j)
                acc[i][j] = __builtin_amdgcn_mfma_scale_f32_16x16x128_f8f6f4(
                    af[i], bfr[j], acc[i][j],
                    0, 0,          // cbsz=fp8(e4m3), blgp=fp8(e4m3)
                    0, 127,        // scale A: byte sel 0, E8M0 127 = 1.0
                    0, 127);       // scale B: identity
        __syncthreads();
    }

    // epilogue: C/D layout col=lane&15, row=quad*4+reg (shape-determined)
    auto epi = [&](auto maskTag) {
        constexpr bool MASK = decltype(maskTag)::value;
        #pragma unroll
        for (int i = 0; i < 4; ++i) {
            #pragma unroll
            for (int reg = 0; reg < 4; ++reg) {
                float s4 = 0.f;
                #pragma unroll
                for (int j = 0; j < 4; ++j) {
                    float t = __builtin_amdgcn_exp2f(
                        fmaf(acc[i][j][reg], K_LOG2E_S, -K_LOG2E_S));
                    if (MASK) {
                        int c = n0 + wcol0 + j * 16 + lanelo;
                        if (c >= C_CLASSES) t = 0.f;
                    }
                    s4 += t;
                }
                #pragma unroll
                for (int off = 1; off < 16; off <<= 1)
                    s4 += __shfl_xor(s4, off);
                if (lanelo == 0)
                    Red[wrow0 + i * 16 + quad * 4 + reg][w & 1] = s4;
            }
        }
    };
    if (chunk == NCHUNK - 1) epi(TrueT{}); else epi(FalseT{});
    __syncthreads();

    if (tid < 128)
        partials[(size_t)(b0 + tid) * NCHUNK + chunk] = Red[tid][0] + Red[tid][1];
}

// -------- finalize: exact label logit + partial sum -> atomic mean NLL --------
__global__ __launch_bounds__(256) void k_fin(const float* __restrict__ emb,
                                             const float* __restrict__ weight,
                                             const float* __restrict__ einv,
                                             const float* __restrict__ winv,
                                             const int* __restrict__ labels,
                                             const float* __restrict__ partials,
                                             float* __restrict__ out) {
    __shared__ float sm[4];
    int widx = threadIdx.x >> 6;
    int b    = blockIdx.x * 4 + widx;    // one wave per row
    int lane = threadIdx.x & 63;
    int label = labels[b];

    const float4* e  = (const float4*)(emb + (size_t)b * D_DIM);
    const float4* wt = (const float4*)(weight + (size_t)label * D_DIM);
    float4 e0 = e[lane],  e1 = e[lane + 64];
    float4 w0 = wt[lane], w1 = wt[lane + 64];
    float dot = e0.x*w0.x + e0.y*w0.y + e0.z*w0.z + e0.w*w0.w
              + e1.x*w1.x + e1.y*w1.y + e1.z*w1.z + e1.w*w1.w;
    float ls = 0.f;
    for (int idx = lane; idx < NCHUNK; idx += 64)
        ls += partials[(size_t)b * NCHUNK + idx];
    #pragma unroll
    for (int off = 32; off; off >>= 1) {
        dot += __shfl_xor(dot, off);
        ls  += __shfl_xor(ls, off);
    }

    float cosv   = dot * einv[b] * winv[label];
    float l_orig = ARC_SCALE * cosv;
    float l_adj  = ARC_SCALE * (cosv - ARC_MARGIN);

    // swap (fp8-accumulated) label term for exact margin-adjusted one
    float s_adj = ls - __expf(l_orig - ARC_SCALE) + __expf(l_adj - ARC_SCALE);
    float v = ARC_SCALE + logf(s_adj) - l_adj;
    if (lane == 0) sm[widx] = v;
    __syncthreads();
    if (threadIdx.x == 0)
        atomicAdd(out, (sm[0] + sm[1] + sm[2] + sm[3]) * (1.0f / (float)B_ROWS));
}

extern "C" void kernel_launch(void* const* d_in, const int* in_sizes, int n_in,
                              void* d_out, int out_size, void* d_ws, size_t ws_size,
                              hipStream_t stream) {
    const float* emb    = (const float*)d_in[0];   // (2048, 512) f32
    const int*   labels = (const int*)d_in[1];     // (2048,)
    const float* weight = (const float*)d_in[2];   // (50000, 512) f32
    float* out = (float*)d_out;

    char* ws = (char*)d_ws;
    uint8_t* wq    = (uint8_t*)(ws + OFF_WQ);
    uint8_t* embq  = (uint8_t*)(ws + OFF_EMBQ);
    float* winv     = (float*)(ws + OFF_WINV);
    float* einv     = (float*)(ws + OFF_EINV);
    float* partials = (float*)(ws + OFF_PART);

    hipMemsetAsync(out, 0, sizeof(float), stream);

    k_prep<<<(C_PAD + B_ROWS) / 4, 256, 0, stream>>>(emb, weight, embq, wq,
                                                     einv, winv);

    dim3 grid(B_ROWS / 128, NCHUNK);   // 16 x 391, row-block fast
    k_gemm<<<grid, 256, 0, stream>>>(embq, wq, partials);

    k_fin<<<B_ROWS / 4, 256, 0, stream>>>(emb, weight, einv, winv, labels,
                                          partials, out);
}

// Round 5
// 268.142 us; speedup vs baseline: 7.1726x; 1.0143x over previous
//
#include <hip/hip_runtime.h>
#include <hip/hip_bf16.h>
#include <math.h>
#include <stdint.h>

// ArcFace loss via MX-fp8 (e4m3, identity scales) MFMA GEMM + fused
// fixed-max softmax. B=2048, D=512, C=50000. Output: scalar mean NLL (f32).
//
// R5: XCD-affinity chunk mapping (each XCD's B slice fits its 4MB L2) +
//     register-prefetch K-loop pipeline (stage kt+1 issued before mfma kt,
//     single-buffered LDS so no occupancy loss). memset folded into k_prep.
//
// Numerics: logits = 30*cos in [-30,30] -> fixed max 30, plain sums:
//   lse = 30 + log(sum_c exp(l_c - 30)); label logit recomputed exactly in
//   fp32 at finalize, so fp8 error only perturbs the softmax denominator.

#define B_ROWS    2048
#define D_DIM     512
#define C_CLASSES 50000
#define C_PAD     50048            // 391 * 128
#define NCHUNK    391
#define CPX       49               // chunks per XCD (8*49=392 slots, 1 unused)
#define ARC_MARGIN 0.3f
#define ARC_SCALE  30.0f
#define ARC_EPS    1e-12f
#define K_LOG2E_S  43.2808512f     // 30 * log2(e)

// workspace layout (bytes)
#define OFF_WQ    0u               // 50048*512 = 25,624,576
#define OFF_EMBQ  25624576u        // 2048*512  =  1,048,576
#define OFF_WINV  26673152u        // 50000*4   =    200,000
#define OFF_EINV  26873152u        // 2048*4    =      8,192
#define OFF_PART  26881344u        // 2048*391*4 = 3,203,072
// total ~30.1 MB

typedef __attribute__((ext_vector_type(8))) int   i32x8;
typedef __attribute__((ext_vector_type(4))) int   i32x4;
typedef __attribute__((ext_vector_type(4))) float f32x4;

typedef __attribute__((address_space(1))) const unsigned int g_u32;
typedef __attribute__((address_space(3))) unsigned int       l_u32;

__device__ __forceinline__ void gload_lds16(const void* g, void* l) {
    // dest is wave-uniform LDS base; HW writes lane i at base + i*16
    g_u32* gp = (g_u32*)(uintptr_t)g;
    l_u32* lp = (l_u32*)(uintptr_t)l;
    __builtin_amdgcn_global_load_lds(gp, lp, 16, 0, 0);
}

// ---------------- prep: rows -> normalized e4m3 + inverse norms ----------------
// gw < C_PAD: weight row (pad rows zero-filled); else: embedding row.
__global__ __launch_bounds__(256) void k_prep(const float* __restrict__ emb,
                                              const float* __restrict__ weight,
                                              uint8_t* __restrict__ embq,
                                              uint8_t* __restrict__ wq,
                                              float* __restrict__ einv,
                                              float* __restrict__ winv,
                                              float* __restrict__ out) {
    if (blockIdx.x == 0 && threadIdx.x == 0) out[0] = 0.f;  // zero for k_fin atomics
    int gw   = (blockIdx.x * blockDim.x + threadIdx.x) >> 6;   // one wave per row
    int lane = threadIdx.x & 63;
    const float* src;
    uint8_t* dst;
    float* invout;
    if (gw < C_PAD) {
        if (gw >= C_CLASSES) {                // zero-fill pad classes
            *(int2*)(wq + (size_t)gw * D_DIM + lane * 8) = make_int2(0, 0);
            return;
        }
        src = weight + (size_t)gw * D_DIM;
        dst = wq + (size_t)gw * D_DIM;
        invout = winv + gw;
    } else {
        int row = gw - C_PAD;
        src = emb + (size_t)row * D_DIM;
        dst = embq + (size_t)row * D_DIM;
        invout = einv + row;
    }
    const float4* r4 = (const float4*)src;
    float4 v0 = r4[lane * 2];
    float4 v1 = r4[lane * 2 + 1];
    float s = v0.x*v0.x + v0.y*v0.y + v0.z*v0.z + v0.w*v0.w
            + v1.x*v1.x + v1.y*v1.y + v1.z*v1.z + v1.w*v1.w;
    #pragma unroll
    for (int off = 32; off; off >>= 1) s += __shfl_xor(s, off);
    float r = 1.0f / fmaxf(sqrtf(s), ARC_EPS);
    if (lane == 0) *invout = r;
    int p0 = __builtin_amdgcn_cvt_pk_fp8_f32(v0.x * r, v0.y * r, 0, false);
    p0     = __builtin_amdgcn_cvt_pk_fp8_f32(v0.z * r, v0.w * r, p0, true);
    int p1 = __builtin_amdgcn_cvt_pk_fp8_f32(v1.x * r, v1.y * r, 0, false);
    p1     = __builtin_amdgcn_cvt_pk_fp8_f32(v1.z * r, v1.w * r, p1, true);
    *(int2*)(dst + lane * 8) = make_int2(p0, p1);
}

struct TrueT  { static constexpr bool value = true;  };
struct FalseT { static constexpr bool value = false; };

// ---------------- GEMM (MX-fp8, identity scales) + softmax partials -----------
__global__ __launch_bounds__(256) void k_gemm(const uint8_t* __restrict__ embq,
                                              const uint8_t* __restrict__ wq,
                                              float* __restrict__ partials) {
    // LDS tile layout: 8 row-blocks of 16 rows; within block [kc 0..7][row 0..15]
    // 16B cells. global_load_lds lane order == layout order -> contiguous,
    // frag ds_read_b128: 16 consecutive lanes read 256 contiguous B (no conflict).
    __shared__ __align__(16) uint8_t A_s[128 * 128];
    __shared__ __align__(16) uint8_t B_s[128 * 128];
    __shared__ float Red[128][2];

    const int tid    = threadIdx.x;
    const int w      = tid >> 6;        // wave 0..3
    const int lane   = tid & 63;
    const int lanelo = lane & 15;
    const int quad   = lane >> 4;
    const int wrow0  = (w >> 1) * 64;   // wave's row base in tile
    const int wcol0  = (w & 1) * 64;    // wave's col base in tile

    // XCD-affinity decode: round-robin dispatch -> xcd = id & 7 (heuristic).
    // XCD k owns chunks [k*49, k*49+48]; its B slice (3.1 MB) + A (1 MB) fit L2.
    const int id    = blockIdx.x;
    const int xcd   = id & 7;
    const int s     = id >> 3;          // 0..783
    const int rb_   = s & 15;           // row-block
    const int chunk = xcd * CPX + (s >> 4);
    if (chunk >= NCHUNK) return;        // 8 pad slots
    const int b0 = rb_ * 128;
    const int n0 = chunk * 128;

    const uint8_t* Abase = embq + (size_t)b0 * D_DIM;
    const uint8_t* Bbase = wq   + (size_t)n0 * D_DIM;

    f32x4 acc[4][4];
    #pragma unroll
    for (int i = 0; i < 4; ++i)
        #pragma unroll
        for (int j = 0; j < 4; ++j)
            acc[i][j] = (f32x4){0.f, 0.f, 0.f, 0.f};

    const int srow = lane & 15;
    const int skc  = lane >> 4;

    auto stage = [&](int kt) {
        const int k0 = kt * 128;
        #pragma unroll
        for (int t = 0; t < 2; ++t) {
            const int rb = w * 2 + t;           // 0..7 across waves
            #pragma unroll
            for (int h = 0; h < 2; ++h) {
                const int kc = h * 4 + skc;     // 0..7
                gload_lds16(Abase + (size_t)(rb * 16 + srow) * D_DIM + k0 + kc * 16,
                            &A_s[rb * 2048 + h * 1024]);
                gload_lds16(Bbase + (size_t)(rb * 16 + srow) * D_DIM + k0 + kc * 16,
                            &B_s[rb * 2048 + h * 1024]);
            }
        }
    };

    stage(0);
    #pragma unroll
    for (int kt = 0; kt < 4; ++kt) {
        __syncthreads();                 // drain vmcnt -> tile kt resident

        i32x8 af[4], bfr[4];             // pull frags to regs (ds_read_b128 x2)
        #pragma unroll
        for (int i = 0; i < 4; ++i) {
            const int rb = (w >> 1) * 4 + i;
            i32x4 lo = *(const i32x4*)&A_s[rb * 2048 + quad * 512 + lanelo * 16];
            i32x4 hi = *(const i32x4*)&A_s[rb * 2048 + quad * 512 + 256 + lanelo * 16];
            af[i] = (i32x8){lo[0], lo[1], lo[2], lo[3], hi[0], hi[1], hi[2], hi[3]};
        }
        #pragma unroll
        for (int j = 0; j < 4; ++j) {
            const int rb = (w & 1) * 4 + j;
            i32x4 lo = *(const i32x4*)&B_s[rb * 2048 + quad * 512 + lanelo * 16];
            i32x4 hi = *(const i32x4*)&B_s[rb * 2048 + quad * 512 + 256 + lanelo * 16];
            bfr[j] = (i32x8){lo[0], lo[1], lo[2], lo[3], hi[0], hi[1], hi[2], hi[3]};
        }
        __syncthreads();                 // all frags in regs -> LDS reusable

        if (kt < 3) stage(kt + 1);       // staging flies under the mfma burst

        #pragma unroll
        for (int i = 0; i < 4; ++i)
            #pragma unroll
            for (int j = 0; j < 4; ++j)
                acc[i][j] = __builtin_amdgcn_mfma_scale_f32_16x16x128_f8f6f4(
                    af[i], bfr[j], acc[i][j],
                    0, 0,          // cbsz=fp8(e4m3), blgp=fp8(e4m3)
                    0, 127,        // scale A: identity (E8M0 127 = 1.0)
                    0, 127);       // scale B: identity
    }

    // epilogue: C/D layout col=lane&15, row=quad*4+reg (shape-determined)
    auto epi = [&](auto maskTag) {
        constexpr bool MASK = decltype(maskTag)::value;
        #pragma unroll
        for (int i = 0; i < 4; ++i) {
            #pragma unroll
            for (int reg = 0; reg < 4; ++reg) {
                float s4 = 0.f;
                #pragma unroll
                for (int j = 0; j < 4; ++j) {
                    float t = __builtin_amdgcn_exp2f(
                        fmaf(acc[i][j][reg], K_LOG2E_S, -K_LOG2E_S));
                    if (MASK) {
                        int c = n0 + wcol0 + j * 16 + lanelo;
                        if (c >= C_CLASSES) t = 0.f;
                    }
                    s4 += t;
                }
                #pragma unroll
                for (int off = 1; off < 16; off <<= 1)
                    s4 += __shfl_xor(s4, off);
                if (lanelo == 0)
                    Red[wrow0 + i * 16 + quad * 4 + reg][w & 1] = s4;
            }
        }
    };
    if (chunk == NCHUNK - 1) epi(TrueT{}); else epi(FalseT{});
    __syncthreads();

    if (tid < 128)
        partials[(size_t)(b0 + tid) * NCHUNK + chunk] = Red[tid][0] + Red[tid][1];
}

// -------- finalize: exact label logit + partial sum -> atomic mean NLL --------
__global__ __launch_bounds__(256) void k_fin(const float* __restrict__ emb,
                                             const float* __restrict__ weight,
                                             const float* __restrict__ einv,
                                             const float* __restrict__ winv,
                                             const int* __restrict__ labels,
                                             const float* __restrict__ partials,
                                             float* __restrict__ out) {
    __shared__ float sm[4];
    int widx = threadIdx.x >> 6;
    int b    = blockIdx.x * 4 + widx;    // one wave per row
    int lane = threadIdx.x & 63;
    int label = labels[b];

    const float4* e  = (const float4*)(emb + (size_t)b * D_DIM);
    const float4* wt = (const float4*)(weight + (size_t)label * D_DIM);
    float4 e0 = e[lane],  e1 = e[lane + 64];
    float4 w0 = wt[lane], w1 = wt[lane + 64];
    float dot = e0.x*w0.x + e0.y*w0.y + e0.z*w0.z + e0.w*w0.w
              + e1.x*w1.x + e1.y*w1.y + e1.z*w1.z + e1.w*w1.w;
    float ls = 0.f;
    for (int idx = lane; idx < NCHUNK; idx += 64)
        ls += partials[(size_t)b * NCHUNK + idx];
    #pragma unroll
    for (int off = 32; off; off >>= 1) {
        dot += __shfl_xor(dot, off);
        ls  += __shfl_xor(ls, off);
    }

    float cosv   = dot * einv[b] * winv[label];
    float l_orig = ARC_SCALE * cosv;
    float l_adj  = ARC_SCALE * (cosv - ARC_MARGIN);

    // swap (fp8-accumulated) label term for exact margin-adjusted one
    float s_adj = ls - __expf(l_orig - ARC_SCALE) + __expf(l_adj - ARC_SCALE);
    float v = ARC_SCALE + logf(s_adj) - l_adj;
    if (lane == 0) sm[widx] = v;
    __syncthreads();
    if (threadIdx.x == 0)
        atomicAdd(out, (sm[0] + sm[1] + sm[2] + sm[3]) * (1.0f / (float)B_ROWS));
}

extern "C" void kernel_launch(void* const* d_in, const int* in_sizes, int n_in,
                              void* d_out, int out_size, void* d_ws, size_t ws_size,
                              hipStream_t stream) {
    const float* emb    = (const float*)d_in[0];   // (2048, 512) f32
    const int*   labels = (const int*)d_in[1];     // (2048,)
    const float* weight = (const float*)d_in[2];   // (50000, 512) f32
    float* out = (float*)d_out;

    char* ws = (char*)d_ws;
    uint8_t* wq    = (uint8_t*)(ws + OFF_WQ);
    uint8_t* embq  = (uint8_t*)(ws + OFF_EMBQ);
    float* winv     = (float*)(ws + OFF_WINV);
    float* einv     = (float*)(ws + OFF_EINV);
    float* partials = (float*)(ws + OFF_PART);

    k_prep<<<(C_PAD + B_ROWS) / 4, 256, 0, stream>>>(emb, weight, embq, wq,
                                                     einv, winv, out);

    k_gemm<<<8 * CPX * 16, 256, 0, stream>>>(embq, wq, partials);

    k_fin<<<B_ROWS / 4, 256, 0, stream>>>(emb, weight, einv, winv, labels,
                                          partials, out);
}